// Round 4
// baseline (414.004 us; speedup 1.0000x reference)
//
#include <hip/hip_runtime.h>
#include <hip/hip_bf16.h>

#define MAXDEG_LDS 128

// ---------- helpers ----------
__device__ __forceinline__ unsigned short f2bf(float f) {
    unsigned u = __float_as_uint(f);
    unsigned r = (u + 0x7fffu + ((u >> 16) & 1u)) >> 16;   // RNE
    return (unsigned short)r;
}
__device__ __forceinline__ float bfu(unsigned short s) {
    return __uint_as_float(((unsigned)s) << 16);
}
__device__ __forceinline__ float blo(unsigned u) { return __uint_as_float(u << 16); }
__device__ __forceinline__ float bhi(unsigned u) { return __uint_as_float(u & 0xffff0000u); }

__device__ __forceinline__ float dot8_relu(const uint4 a, const uint4 b, const float* w2r) {
    float acc;
    acc  = w2r[0] * fmaxf(blo(a.x) + blo(b.x), 0.f);
    acc += w2r[1] * fmaxf(bhi(a.x) + bhi(b.x), 0.f);
    acc += w2r[2] * fmaxf(blo(a.y) + blo(b.y), 0.f);
    acc += w2r[3] * fmaxf(bhi(a.y) + bhi(b.y), 0.f);
    acc += w2r[4] * fmaxf(blo(a.z) + blo(b.z), 0.f);
    acc += w2r[5] * fmaxf(bhi(a.z) + bhi(b.z), 0.f);
    acc += w2r[6] * fmaxf(blo(a.w) + blo(b.w), 0.f);
    acc += w2r[7] * fmaxf(bhi(a.w) + bhi(b.w), 0.f);
    return acc;
}

// ---------- CSR build ----------
__global__ void hist_kernel(const int* __restrict__ ei, int* __restrict__ counts, int E) {
    int e = blockIdx.x * 256 + threadIdx.x;
    if (e < E) atomicAdd(&counts[ei[E + e]], 1);
}

__global__ void scanA_kernel(const int* __restrict__ counts, int* __restrict__ bsum, int N) {
    __shared__ int red[256];
    int t = threadIdx.x;
    int i = blockIdx.x * 256 + t;
    red[t] = (i < N) ? counts[i] : 0;
    __syncthreads();
    for (int s = 128; s > 0; s >>= 1) {
        if (t < s) red[t] += red[t + s];
        __syncthreads();
    }
    if (t == 0) bsum[blockIdx.x] = red[0];
}

// nb <= 256 required (N <= 65536)
__global__ void scanB_kernel(const int* __restrict__ bsum, int* __restrict__ boff,
                             int* __restrict__ rowptr, int nb, int N) {
    __shared__ int sc[256];
    int t = threadIdx.x;
    int v = (t < nb) ? bsum[t] : 0;
    sc[t] = v;
    __syncthreads();
    for (int off = 1; off < 256; off <<= 1) {
        int a = (t >= off) ? sc[t - off] : 0;
        __syncthreads();
        sc[t] += a;
        __syncthreads();
    }
    if (t < nb) boff[t] = sc[t] - v;        // exclusive
    if (t == 255) rowptr[N] = sc[255];      // total
}

__global__ void scanC_kernel(const int* __restrict__ counts, const int* __restrict__ boff,
                             int* __restrict__ rowptr, int* __restrict__ cursor, int N) {
    __shared__ int sc[256];
    int t = threadIdx.x;
    int i = blockIdx.x * 256 + t;
    int v = (i < N) ? counts[i] : 0;
    sc[t] = v;
    __syncthreads();
    for (int off = 1; off < 256; off <<= 1) {
        int a = (t >= off) ? sc[t - off] : 0;
        __syncthreads();
        sc[t] += a;
        __syncthreads();
    }
    int excl = sc[t] - v + boff[blockIdx.x];
    if (i < N) { rowptr[i] = excl; cursor[i] = excl; }
}

__global__ void bucket_kernel(const int* __restrict__ ei, int* __restrict__ cursor,
                              int* __restrict__ srt_s, int* __restrict__ srt_e, int E) {
    int e = blockIdx.x * 256 + threadIdx.x;
    if (e >= E) return;
    int d = ei[E + e];
    int pos = atomicAdd(&cursor[d], 1);
    srt_s[pos] = ei[e];
    srt_e[pos] = e;
}

// ---------- node projection: PS[n][0:128]=x@w1_top+b1, PD[n][0:128]=x@w1_bot ----------
__global__ __launch_bounds__(256) void proj_kernel(
    const float* __restrict__ x, const float* __restrict__ w1, const float* __restrict__ b1,
    unsigned short* __restrict__ PS, unsigned short* __restrict__ PD, int N)
{
    __shared__ unsigned short wl[64 * 256];  // 32 KB
    __shared__ float xs[32 * 64];            // 8 KB
    const int t = threadIdx.x;

    for (int i = t; i < 64 * 256; i += 256) {
        int k = i >> 8, j = i & 255;
        float w = (j < 128) ? w1[k * 128 + j] : w1[(64 + k) * 128 + (j - 128)];
        wl[i] = f2bf(w);
    }
    const int n0 = blockIdx.x * 32;
    for (int i = t; i < 32 * 64; i += 256) {
        int n = n0 + (i >> 6);
        xs[i] = (n < N) ? x[(size_t)n * 64 + (i & 63)] : 0.f;
    }
    __syncthreads();

    const int jg = t & 63;
    const int ng = t >> 6;
    const int j0 = jg * 4;

    float acc[8][4];
#pragma unroll
    for (int i = 0; i < 8; ++i)
#pragma unroll
        for (int c = 0; c < 4; ++c) acc[i][c] = 0.f;

    for (int k = 0; k < 64; k += 4) {
        float wv[4][4];
#pragma unroll
        for (int kk = 0; kk < 4; ++kk) {
            ushort4 wu = *(const ushort4*)&wl[(k + kk) * 256 + j0];
            wv[kk][0] = bfu(wu.x); wv[kk][1] = bfu(wu.y);
            wv[kk][2] = bfu(wu.z); wv[kk][3] = bfu(wu.w);
        }
#pragma unroll
        for (int i = 0; i < 8; ++i) {
            const float4 xv = *(const float4*)&xs[(ng * 8 + i) * 64 + k];
#pragma unroll
            for (int c = 0; c < 4; ++c)
                acc[i][c] += xv.x * wv[0][c] + xv.y * wv[1][c] + xv.z * wv[2][c] + xv.w * wv[3][c];
        }
    }

    float bb[4] = {0.f, 0.f, 0.f, 0.f};
    if (j0 < 128) {
#pragma unroll
        for (int c = 0; c < 4; ++c) bb[c] = b1[j0 + c];
    }

#pragma unroll
    for (int i = 0; i < 8; ++i) {
        int n = n0 + ng * 8 + i;
        if (n < N) {
            ushort4 st;
            st.x = f2bf(acc[i][0] + bb[0]);
            st.y = f2bf(acc[i][1] + bb[1]);
            st.z = f2bf(acc[i][2] + bb[2]);
            st.w = f2bf(acc[i][3] + bb[3]);
            if (j0 < 128) *(ushort4*)(PS + (size_t)n * 128 + j0) = st;
            else          *(ushort4*)(PD + (size_t)n * 128 + (j0 - 128)) = st;
        }
    }
}

// ---------- main: one 16-lane slot per dst node; zero atomics ----------
__global__ __launch_bounds__(256) void gat_main_kernel(
    const unsigned short* __restrict__ PS, const unsigned short* __restrict__ PD,
    const int* __restrict__ rowptr, const int* __restrict__ srt_s, const int* __restrict__ srt_e,
    const float* __restrict__ y, const float* __restrict__ w2, const float* __restrict__ b2,
    float* __restrict__ yhat, float* __restrict__ alpha, int N)
{
    __shared__ float evs[16][MAXDEG_LDS];   // 8 KB
    const int t = threadIdx.x;
    const int lane = t & 15;
    const int slot = t >> 4;
    const int d = blockIdx.x * 16 + slot;

    float w2r[8];
#pragma unroll
    for (int c = 0; c < 8; ++c) w2r[c] = w2[lane * 8 + c];
    const float b2s = b2[0];

    if (d >= N) return;

    const uint4 pd = *(const uint4*)(PD + (size_t)d * 128 + lane * 8);
    const int beg = rowptr[d], end = rowptr[d + 1];

    float dsum = 0.f, ysum = 0.f;
    int i = beg;
    for (; i + 1 < end; i += 2) {
        const int s0 = srt_s[i], s1 = srt_s[i + 1];
        const uint4 a0 = *(const uint4*)(PS + (size_t)s0 * 128 + lane * 8);
        const uint4 a1 = *(const uint4*)(PS + (size_t)s1 * 128 + lane * 8);
        const float y0 = y[s0], y1 = y[s1];

        float acc0 = dot8_relu(a0, pd, w2r);
        float acc1 = dot8_relu(a1, pd, w2r);
        acc0 += __shfl_xor(acc0, 1);  acc1 += __shfl_xor(acc1, 1);
        acc0 += __shfl_xor(acc0, 2);  acc1 += __shfl_xor(acc1, 2);
        acc0 += __shfl_xor(acc0, 4);  acc1 += __shfl_xor(acc1, 4);
        acc0 += __shfl_xor(acc0, 8);  acc1 += __shfl_xor(acc1, 8);

        const float ev0 = __expf(acc0 + b2s);
        const float ev1 = __expf(acc1 + b2s);
        dsum += ev0 + ev1;
        ysum += y0 * ev0 + y1 * ev1;

        const int k = i - beg;
        if (lane == 0 && k < MAXDEG_LDS)     evs[slot][k] = ev0;
        if (lane == 8 && k + 1 < MAXDEG_LDS) evs[slot][k + 1] = ev1;
    }
    if (i < end) {
        const int s0 = srt_s[i];
        const uint4 a0 = *(const uint4*)(PS + (size_t)s0 * 128 + lane * 8);
        const float y0 = y[s0];
        float acc0 = dot8_relu(a0, pd, w2r);
        acc0 += __shfl_xor(acc0, 1);
        acc0 += __shfl_xor(acc0, 2);
        acc0 += __shfl_xor(acc0, 4);
        acc0 += __shfl_xor(acc0, 8);
        const float ev0 = __expf(acc0 + b2s);
        dsum += ev0;
        ysum += y0 * ev0;
        const int k = i - beg;
        if (lane == 0 && k < MAXDEG_LDS) evs[slot][k] = ev0;
    }

    const float inv = (dsum > 0.f) ? 1.f / dsum : 0.f;
    if (lane == 0) yhat[d] = ysum * inv;

    const int deg = end - beg;
    for (int k = lane; k < deg; k += 16) {
        float ev;
        if (k < MAXDEG_LDS) {
            ev = evs[slot][k];
        } else {
            // cold fallback (deg > 128 never occurs for this dataset): scalar recompute
            const int s0 = srt_s[beg + k];
            float acc = 0.f;
#pragma unroll
            for (int c = 0; c < 16; ++c) {
                const uint4 a = *(const uint4*)(PS + (size_t)s0 * 128 + c * 8);
                const uint4 b = *(const uint4*)(PD + (size_t)d * 128 + c * 8);
                acc += w2[c * 8 + 0] * fmaxf(blo(a.x) + blo(b.x), 0.f);
                acc += w2[c * 8 + 1] * fmaxf(bhi(a.x) + bhi(b.x), 0.f);
                acc += w2[c * 8 + 2] * fmaxf(blo(a.y) + blo(b.y), 0.f);
                acc += w2[c * 8 + 3] * fmaxf(bhi(a.y) + bhi(b.y), 0.f);
                acc += w2[c * 8 + 4] * fmaxf(blo(a.z) + blo(b.z), 0.f);
                acc += w2[c * 8 + 5] * fmaxf(bhi(a.z) + bhi(b.z), 0.f);
                acc += w2[c * 8 + 6] * fmaxf(blo(a.w) + blo(b.w), 0.f);
                acc += w2[c * 8 + 7] * fmaxf(bhi(a.w) + bhi(b.w), 0.f);
            }
            ev = __expf(acc + b2s);
        }
        alpha[srt_e[beg + k]] = ev * inv;
    }
}

extern "C" void kernel_launch(void* const* d_in, const int* in_sizes, int n_in,
                              void* d_out, int out_size, void* d_ws, size_t ws_size,
                              hipStream_t stream) {
    const float* x  = (const float*)d_in[0];
    const float* y  = (const float*)d_in[1];
    const int*   ei = (const int*)d_in[2];
    const float* w1 = (const float*)d_in[3];
    const float* b1 = (const float*)d_in[4];
    const float* w2 = (const float*)d_in[5];
    const float* b2 = (const float*)d_in[6];

    const int N = in_sizes[1];
    const int E = in_sizes[2] / 2;

    float* out   = (float*)d_out;
    float* yhat  = out;          // [N]
    float* alpha = out + N;      // [E]

    // workspace layout (16B-aligned chunks)
    char* ws = (char*)d_ws;
    size_t off = 0;
    unsigned short* PS = (unsigned short*)(ws + off); off += (size_t)N * 128 * 2;
    unsigned short* PD = (unsigned short*)(ws + off); off += (size_t)N * 128 * 2;
    int* counts = (int*)(ws + off); off += ((size_t)N * 4 + 15) & ~15ull;
    int* rowptr = (int*)(ws + off); off += ((size_t)(N + 1) * 4 + 15) & ~15ull;
    int* cursor = (int*)(ws + off); off += ((size_t)N * 4 + 15) & ~15ull;
    int* bsum   = (int*)(ws + off); off += 256 * 4;
    int* boff   = (int*)(ws + off); off += 256 * 4;
    int* srt_s  = (int*)(ws + off); off += (size_t)E * 4;
    int* srt_e  = (int*)(ws + off); off += (size_t)E * 4;

    const int nb = (N + 255) / 256;   // 196 for N=50000 (must be <= 256)

    hipMemsetAsync(counts, 0, (size_t)N * 4, stream);
    hist_kernel<<<(E + 255) / 256, 256, 0, stream>>>(ei, counts, E);
    scanA_kernel<<<nb, 256, 0, stream>>>(counts, bsum, N);
    scanB_kernel<<<1, 256, 0, stream>>>(bsum, boff, rowptr, nb, N);
    scanC_kernel<<<nb, 256, 0, stream>>>(counts, boff, rowptr, cursor, N);
    bucket_kernel<<<(E + 255) / 256, 256, 0, stream>>>(ei, cursor, srt_s, srt_e, E);
    proj_kernel<<<(N + 31) / 32, 256, 0, stream>>>(x, w1, b1, PS, PD, N);
    gat_main_kernel<<<(N + 15) / 16, 256, 0, stream>>>(PS, PD, rowptr, srt_s, srt_e,
                                                       y, w2, b2, yhat, alpha, N);
}

// Round 5
// 324.674 us; speedup vs baseline: 1.2751x; 1.2751x over previous
//
#include <hip/hip_runtime.h>
#include <hip/hip_bf16.h>

// ---------- helpers ----------
__device__ __forceinline__ unsigned short f2bf(float f) {
    unsigned u = __float_as_uint(f);
    unsigned r = (u + 0x7fffu + ((u >> 16) & 1u)) >> 16;   // RNE
    return (unsigned short)r;
}
__device__ __forceinline__ float bfu(unsigned short s) {
    return __uint_as_float(((unsigned)s) << 16);
}
__device__ __forceinline__ float blo(unsigned u) { return __uint_as_float(u << 16); }
__device__ __forceinline__ float bhi(unsigned u) { return __uint_as_float(u & 0xffff0000u); }

__device__ __forceinline__ float dot8_relu(const uint4 a, const uint4 b, const float* w2r) {
    float acc;
    acc  = w2r[0] * fmaxf(blo(a.x) + blo(b.x), 0.f);
    acc += w2r[1] * fmaxf(bhi(a.x) + bhi(b.x), 0.f);
    acc += w2r[2] * fmaxf(blo(a.y) + blo(b.y), 0.f);
    acc += w2r[3] * fmaxf(bhi(a.y) + bhi(b.y), 0.f);
    acc += w2r[4] * fmaxf(blo(a.z) + blo(b.z), 0.f);
    acc += w2r[5] * fmaxf(bhi(a.z) + bhi(b.z), 0.f);
    acc += w2r[6] * fmaxf(blo(a.w) + blo(b.w), 0.f);
    acc += w2r[7] * fmaxf(bhi(a.w) + bhi(b.w), 0.f);
    return acc;
}

// ---------- kernel 1: init (denom and yhat must start at zero) ----------
__global__ void init_kernel(float* __restrict__ denom, float* __restrict__ yhat, int N) {
    int i = blockIdx.x * 256 + threadIdx.x;
    if (i < N) { denom[i] = 0.f; yhat[i] = 0.f; }
}

// ---------- kernel 2: node projection  P[n][0:128]=x@w1_top+b1, P[n][128:256]=x@w1_bot ----------
__global__ __launch_bounds__(256) void proj_kernel(
    const float* __restrict__ x, const float* __restrict__ w1, const float* __restrict__ b1,
    unsigned short* __restrict__ P, int N)
{
    __shared__ unsigned short wl[64 * 256];  // 32 KB
    __shared__ float xs[32 * 64];            // 8 KB
    const int t = threadIdx.x;

    for (int i = t; i < 64 * 256; i += 256) {
        int k = i >> 8, j = i & 255;
        float w = (j < 128) ? w1[k * 128 + j] : w1[(64 + k) * 128 + (j - 128)];
        wl[i] = f2bf(w);
    }
    const int n0 = blockIdx.x * 32;
    for (int i = t; i < 32 * 64; i += 256) {
        int n = n0 + (i >> 6);
        xs[i] = (n < N) ? x[(size_t)n * 64 + (i & 63)] : 0.f;
    }
    __syncthreads();

    const int jg = t & 63;
    const int ng = t >> 6;
    const int j0 = jg * 4;

    float acc[8][4];
#pragma unroll
    for (int i = 0; i < 8; ++i)
#pragma unroll
        for (int c = 0; c < 4; ++c) acc[i][c] = 0.f;

    for (int k = 0; k < 64; k += 4) {
        float wv[4][4];
#pragma unroll
        for (int kk = 0; kk < 4; ++kk) {
            ushort4 wu = *(const ushort4*)&wl[(k + kk) * 256 + j0];
            wv[kk][0] = bfu(wu.x); wv[kk][1] = bfu(wu.y);
            wv[kk][2] = bfu(wu.z); wv[kk][3] = bfu(wu.w);
        }
#pragma unroll
        for (int i = 0; i < 8; ++i) {
            const float4 xv = *(const float4*)&xs[(ng * 8 + i) * 64 + k];
#pragma unroll
            for (int c = 0; c < 4; ++c)
                acc[i][c] += xv.x * wv[0][c] + xv.y * wv[1][c] + xv.z * wv[2][c] + xv.w * wv[3][c];
        }
    }

    float bb[4] = {0.f, 0.f, 0.f, 0.f};
    if (j0 < 128) {
#pragma unroll
        for (int c = 0; c < 4; ++c) bb[c] = b1[j0 + c];
    }

#pragma unroll
    for (int i = 0; i < 8; ++i) {
        int n = n0 + ng * 8 + i;
        if (n < N) {
            ushort4 st;
            st.x = f2bf(acc[i][0] + bb[0]);
            st.y = f2bf(acc[i][1] + bb[1]);
            st.z = f2bf(acc[i][2] + bb[2]);
            st.w = f2bf(acc[i][3] + bb[3]);
            *(ushort4*)(P + (size_t)n * 256 + j0) = st;
        }
    }
}

// ---------- kernel 3: edge logit -> exp -> elog, ONE hidden atomic stream (denom) ----------
// 16 lanes per edge (R1-proven shape: one fire-and-forget atomic hides under
// the 819MB gather).
__global__ __launch_bounds__(256) void edge_logit_kernel(
    const unsigned short* __restrict__ P, const int* __restrict__ ei,
    const float* __restrict__ w2, const float* __restrict__ b2,
    float* __restrict__ elog, float* __restrict__ denom, int E)
{
    const int lane = threadIdx.x & 15;
    float w2r[8];
#pragma unroll
    for (int c = 0; c < 8; ++c) w2r[c] = w2[lane * 8 + c];
    const float b2s = b2[0];

    const int slot = (blockIdx.x * 256 + threadIdx.x) >> 4;
    const int nslots = (gridDim.x * 256) >> 4;

    for (int e = slot; e < E; e += nslots) {
        const int s = ei[e];
        const int d = ei[E + e];
        const uint4 a = *(const uint4*)(P + (size_t)s * 256 + lane * 8);
        const uint4 b = *(const uint4*)(P + (size_t)d * 256 + 128 + lane * 8);

        float acc = dot8_relu(a, b, w2r);
        acc += __shfl_xor(acc, 1);
        acc += __shfl_xor(acc, 2);
        acc += __shfl_xor(acc, 4);
        acc += __shfl_xor(acc, 8);

        if (lane == 0) {
            float ev = __expf(acc + b2s);
            elog[e] = ev;
            atomicAdd(&denom[d], ev);
        }
    }
}

// ---------- kernel 4: inv_d = 1/denom ----------
__global__ void node_inv_kernel(const float* __restrict__ denom,
                                float* __restrict__ inv_d, int N) {
    int i = blockIdx.x * 256 + threadIdx.x;
    if (i >= N) return;
    float dnm = denom[i];
    inv_d[i] = (dnm != 0.f) ? 1.0f / dnm : 0.f;
}

// ---------- kernel 5: alpha = ev*inv_d[d] (stream write) + yhat[d] += y[s]*alpha (ONE atomic stream) ----------
__global__ __launch_bounds__(256) void alpha_yhat_kernel(
    const int* __restrict__ ei, const float* __restrict__ y,
    float* __restrict__ elog, const float* __restrict__ inv_d,
    float* __restrict__ yhat, int E)
{
    int e = blockIdx.x * 256 + threadIdx.x;
    if (e >= E) return;
    int s = ei[e];
    int d = ei[E + e];
    float alpha = elog[e] * inv_d[d];
    elog[e] = alpha;
    atomicAdd(&yhat[d], y[s] * alpha);
}

extern "C" void kernel_launch(void* const* d_in, const int* in_sizes, int n_in,
                              void* d_out, int out_size, void* d_ws, size_t ws_size,
                              hipStream_t stream) {
    const float* x  = (const float*)d_in[0];
    const float* y  = (const float*)d_in[1];
    const int*   ei = (const int*)d_in[2];
    const float* w1 = (const float*)d_in[3];
    const float* b1 = (const float*)d_in[4];
    const float* w2 = (const float*)d_in[5];
    const float* b2 = (const float*)d_in[6];

    const int N = in_sizes[1];
    const int E = in_sizes[2] / 2;

    float* out  = (float*)d_out;
    float* yhat = out;          // [N]
    float* elog = out + N;      // [E] — exp values, then alpha in place

    char* ws = (char*)d_ws;
    unsigned short* P = (unsigned short*)ws;                   // N*256 bf16 = 25.6 MB
    size_t Pbytes = (size_t)N * 256 * sizeof(unsigned short);
    float* denom = (float*)(ws + Pbytes);                      // N f32
    float* inv_d = denom + N;                                  // N f32

    init_kernel<<<(N + 255) / 256, 256, 0, stream>>>(denom, yhat, N);
    proj_kernel<<<(N + 31) / 32, 256, 0, stream>>>(x, w1, b1, P, N);
    edge_logit_kernel<<<2048, 256, 0, stream>>>(P, ei, w2, b2, elog, denom, E);
    node_inv_kernel<<<(N + 255) / 256, 256, 0, stream>>>(denom, inv_d, N);
    alpha_yhat_kernel<<<(E + 255) / 256, 256, 0, stream>>>(ei, y, elog, inv_d, yhat, E);
}

// Round 6
// 242.008 us; speedup vs baseline: 1.7107x; 1.3416x over previous
//
#include <hip/hip_runtime.h>
#include <hip/hip_bf16.h>

// ---------- helpers ----------
__device__ __forceinline__ unsigned short f2bf(float f) {
    unsigned u = __float_as_uint(f);
    unsigned r = (u + 0x7fffu + ((u >> 16) & 1u)) >> 16;   // RNE
    return (unsigned short)r;
}
__device__ __forceinline__ float bfu(unsigned short s) {
    return __uint_as_float(((unsigned)s) << 16);
}
__device__ __forceinline__ float blo(unsigned u) { return __uint_as_float(u << 16); }
__device__ __forceinline__ float bhi(unsigned u) { return __uint_as_float(u & 0xffff0000u); }

__device__ __forceinline__ float dot8_relu(const uint4 a, const uint4 b, const float* w2r) {
    float acc;
    acc  = w2r[0] * fmaxf(blo(a.x) + blo(b.x), 0.f);
    acc += w2r[1] * fmaxf(bhi(a.x) + bhi(b.x), 0.f);
    acc += w2r[2] * fmaxf(blo(a.y) + blo(b.y), 0.f);
    acc += w2r[3] * fmaxf(bhi(a.y) + bhi(b.y), 0.f);
    acc += w2r[4] * fmaxf(blo(a.z) + blo(b.z), 0.f);
    acc += w2r[5] * fmaxf(bhi(a.z) + bhi(b.z), 0.f);
    acc += w2r[6] * fmaxf(blo(a.w) + blo(b.w), 0.f);
    acc += w2r[7] * fmaxf(bhi(a.w) + bhi(b.w), 0.f);
    return acc;
}

// ---------- kernel 1: node projection  P[n][0:128]=x@w1_top+b1, P[n][128:256]=x@w1_bot ----------
__global__ __launch_bounds__(256) void proj_kernel(
    const float* __restrict__ x, const float* __restrict__ w1, const float* __restrict__ b1,
    unsigned short* __restrict__ P, int N)
{
    __shared__ unsigned short wl[64 * 256];  // 32 KB
    __shared__ float xs[32 * 64];            // 8 KB
    const int t = threadIdx.x;

    for (int i = t; i < 64 * 256; i += 256) {
        int k = i >> 8, j = i & 255;
        float w = (j < 128) ? w1[k * 128 + j] : w1[(64 + k) * 128 + (j - 128)];
        wl[i] = f2bf(w);
    }
    const int n0 = blockIdx.x * 32;
    for (int i = t; i < 32 * 64; i += 256) {
        int n = n0 + (i >> 6);
        xs[i] = (n < N) ? x[(size_t)n * 64 + (i & 63)] : 0.f;
    }
    __syncthreads();

    const int jg = t & 63;
    const int ng = t >> 6;
    const int j0 = jg * 4;

    float acc[8][4];
#pragma unroll
    for (int i = 0; i < 8; ++i)
#pragma unroll
        for (int c = 0; c < 4; ++c) acc[i][c] = 0.f;

    for (int k = 0; k < 64; k += 4) {
        float wv[4][4];
#pragma unroll
        for (int kk = 0; kk < 4; ++kk) {
            ushort4 wu = *(const ushort4*)&wl[(k + kk) * 256 + j0];
            wv[kk][0] = bfu(wu.x); wv[kk][1] = bfu(wu.y);
            wv[kk][2] = bfu(wu.z); wv[kk][3] = bfu(wu.w);
        }
#pragma unroll
        for (int i = 0; i < 8; ++i) {
            const float4 xv = *(const float4*)&xs[(ng * 8 + i) * 64 + k];
#pragma unroll
            for (int c = 0; c < 4; ++c)
                acc[i][c] += xv.x * wv[0][c] + xv.y * wv[1][c] + xv.z * wv[2][c] + xv.w * wv[3][c];
        }
    }

    float bb[4] = {0.f, 0.f, 0.f, 0.f};
    if (j0 < 128) {
#pragma unroll
        for (int c = 0; c < 4; ++c) bb[c] = b1[j0 + c];
    }

#pragma unroll
    for (int i = 0; i < 8; ++i) {
        int n = n0 + ng * 8 + i;
        if (n < N) {
            ushort4 st;
            st.x = f2bf(acc[i][0] + bb[0]);
            st.y = f2bf(acc[i][1] + bb[1]);
            st.z = f2bf(acc[i][2] + bb[2]);
            st.w = f2bf(acc[i][3] + bb[3]);
            *(ushort4*)(P + (size_t)n * 256 + j0) = st;
        }
    }
}

// ---------- kernel 2: edge logit -> exp -> elog; ONE packed u64 atomic per edge ----------
// lo 32 bits: Sigma round(ev * 2^16)        (always >= 0, sum < 2^31: no carry into hi)
// hi 32 bits: Sigma round(y[s]*ev * 2^14)   (two's-complement, |sum| < 2^31)
__global__ __launch_bounds__(256) void edge_logit_kernel(
    const unsigned short* __restrict__ P, const int* __restrict__ ei,
    const float* __restrict__ y,
    const float* __restrict__ w2, const float* __restrict__ b2,
    float* __restrict__ elog, unsigned long long* __restrict__ agg, int E)
{
    const int lane = threadIdx.x & 15;
    float w2r[8];
#pragma unroll
    for (int c = 0; c < 8; ++c) w2r[c] = w2[lane * 8 + c];
    const float b2s = b2[0];

    const int slot = (blockIdx.x * 256 + threadIdx.x) >> 4;
    const int nslots = (gridDim.x * 256) >> 4;

    for (int e = slot; e < E; e += nslots) {
        const int s = ei[e];
        const int d = ei[E + e];
        const uint4 a = *(const uint4*)(P + (size_t)s * 256 + lane * 8);
        const uint4 b = *(const uint4*)(P + (size_t)d * 256 + 128 + lane * 8);

        float acc = dot8_relu(a, b, w2r);
        acc += __shfl_xor(acc, 1);
        acc += __shfl_xor(acc, 2);
        acc += __shfl_xor(acc, 4);
        acc += __shfl_xor(acc, 8);

        if (lane == 0) {
            float ev = __expf(acc + b2s);
            elog[e] = ev;
            // fixed-point pack (clamps are >1e5-sigma insurance, cost ~nothing)
            float flo = fminf(ev * 65536.f, 1.0e9f);
            float fhi = fmaxf(fminf(y[s] * ev * 16384.f, 1.0e9f), -1.0e9f);
            unsigned int qlo = (unsigned int)__float2int_rn(flo);
            int          qhi = __float2int_rn(fhi);
            unsigned long long packed =
                ((unsigned long long)(unsigned int)qhi << 32) | (unsigned long long)qlo;
            atomicAdd(&agg[d], packed);
        }
    }
}

// ---------- kernel 3: decode agg -> inv_d, yhat ----------
__global__ void node_decode_kernel(const unsigned long long* __restrict__ agg,
                                   float* __restrict__ inv_d,
                                   float* __restrict__ yhat, int N) {
    int i = blockIdx.x * 256 + threadIdx.x;
    if (i >= N) return;
    unsigned long long v = agg[i];
    unsigned int lo = (unsigned int)(v & 0xffffffffull);
    int          hi = (int)(v >> 32);
    if (lo != 0u) {
        float flo = (float)lo;
        yhat[i]  = 4.0f * (float)hi / flo;   // (hi/2^14)/(lo/2^16)
        inv_d[i] = 65536.0f / flo;           // 1/denom
    } else {
        yhat[i]  = 0.f;
        inv_d[i] = 0.f;
    }
}

// ---------- kernel 4: alpha = ev * inv_d[dst]  (pure streaming, zero atomics) ----------
__global__ __launch_bounds__(256) void alpha_norm_kernel(
    const int* __restrict__ ei, float* __restrict__ elog,
    const float* __restrict__ inv_d, int E)
{
    int e = blockIdx.x * 256 + threadIdx.x;
    if (e >= E) return;
    int d = ei[E + e];
    elog[e] = elog[e] * inv_d[d];
}

extern "C" void kernel_launch(void* const* d_in, const int* in_sizes, int n_in,
                              void* d_out, int out_size, void* d_ws, size_t ws_size,
                              hipStream_t stream) {
    const float* x  = (const float*)d_in[0];
    const float* y  = (const float*)d_in[1];
    const int*   ei = (const int*)d_in[2];
    const float* w1 = (const float*)d_in[3];
    const float* b1 = (const float*)d_in[4];
    const float* w2 = (const float*)d_in[5];
    const float* b2 = (const float*)d_in[6];

    const int N = in_sizes[1];
    const int E = in_sizes[2] / 2;

    float* out  = (float*)d_out;
    float* yhat = out;          // [N]
    float* elog = out + N;      // [E] — exp values, then alpha in place

    char* ws = (char*)d_ws;
    unsigned short* P = (unsigned short*)ws;                   // N*256 bf16 = 25.6 MB
    size_t Pbytes = (size_t)N * 256 * sizeof(unsigned short);
    unsigned long long* agg = (unsigned long long*)(ws + Pbytes);  // N u64
    float* inv_d = (float*)(ws + Pbytes + (size_t)N * 8);          // N f32

    hipMemsetAsync(agg, 0, (size_t)N * 8, stream);
    proj_kernel<<<(N + 31) / 32, 256, 0, stream>>>(x, w1, b1, P, N);
    edge_logit_kernel<<<2048, 256, 0, stream>>>(P, ei, y, w2, b2, elog, agg, E);
    node_decode_kernel<<<(N + 255) / 256, 256, 0, stream>>>(agg, inv_d, yhat, N);
    alpha_norm_kernel<<<(E + 255) / 256, 256, 0, stream>>>(ei, elog, inv_d, E);
}